// Round 1
// baseline (757.890 us; speedup 1.0000x reference)
//
#include <hip/hip_runtime.h>
#include <math.h>

#define BATCH 8
#define CCH 256
#define HW 40000
#define KSEL 8000
#define EPS_LN 1e-6f
#define EPS_COS 1e-8f

#define NCOPY 16
#define HSTRIDE 257   // 256 bins + 1 pad word so copies land in rotated banks

// Monotonic map: larger float -> larger uint key
__device__ __forceinline__ unsigned int mono_key(float x) {
  unsigned int u = __float_as_uint(x);
  return (u & 0x80000000u) ? ~u : (u | 0x80000000u);
}

// One thread per pixel: stream C=256 channels of both tensors once,
// emit raw score (sum a^2) and contribution (1 - cosine_sim of channel-normed vecs).
__global__ __launch_bounds__(256) void pixel_stats_kernel(
    const float* __restrict__ A, const float* __restrict__ B,
    float* __restrict__ score, float* __restrict__ contrib) {
  int tid = blockIdx.x * blockDim.x + threadIdx.x;
  if (tid >= BATCH * HW) return;
  int b = tid / HW;
  int p = tid - b * HW;
  const float* a  = A + (size_t)b * CCH * HW + p;
  const float* bb = B + (size_t)b * CCH * HW + p;

  float sa = 0.f, ssa = 0.f, sb = 0.f, ssb = 0.f, dab = 0.f;
#pragma unroll 8
  for (int c = 0; c < CCH; ++c) {
    float x = a[c * HW];
    float y = bb[c * HW];
    sa  += x;     ssa += x * x;
    sb  += y;     ssb += y * y;
    dab += x * y;
  }

  score[tid] = ssa;  // reference scores on RAW bev_map

  const float invC = 1.0f / (float)CCH;
  float mua = sa * invC, mub = sb * invC;
  float cssa = fmaxf(ssa - (float)CCH * mua * mua, 0.f);  // sum (a-mu)^2
  float cssb = fmaxf(ssb - (float)CCH * mub * mub, 0.f);
  float cdot = dab - (float)CCH * mua * mub;              // sum (a-mua)(b-mub)

  // reference eps semantics: sigma = std(ddof=1) + EPS_LN, norms clamped at EPS_COS
  float siga = sqrtf(cssa / (float)(CCH - 1)) + EPS_LN;
  float sigb = sqrtf(cssb / (float)(CCH - 1)) + EPS_LN;
  float num = cdot / (siga * sigb);
  float na = sqrtf(cssa) / siga;
  float nb = sqrtf(cssb) / sigb;
  float sim = num / (fmaxf(na, EPS_COS) * fmaxf(nb, EPS_COS));
  contrib[tid] = 1.0f - sim;
}

// One block per batch: 4-round (8-bit digit) MSB-first radix select of the
// k-th largest score key, then sum contributions of the top-k set.
__global__ __launch_bounds__(1024) void topk_sum_kernel(
    const float* __restrict__ score, const float* __restrict__ contrib,
    float* __restrict__ batch_sums) {
  int b = blockIdx.x;
  const float* s  = score   + b * HW;
  const float* ct = contrib + b * HW;

  __shared__ unsigned int hist[NCOPY * HSTRIDE];
  __shared__ unsigned int sel_digit, sel_remaining, tie_cnt;
  __shared__ float red[1024];

  const int copy = (threadIdx.x >> 6) & (NCOPY - 1);  // one hist copy per wave
  unsigned int prefix = 0;
  unsigned int remaining = KSEL;

  for (int round = 0; round < 4; ++round) {
    int shift = 24 - 8 * round;
    for (int i = threadIdx.x; i < NCOPY * HSTRIDE; i += blockDim.x) hist[i] = 0;
    __syncthreads();

    for (int i = threadIdx.x; i < HW; i += blockDim.x) {
      unsigned int key = mono_key(s[i]);
      if (round == 0 || (key >> (shift + 8)) == prefix) {
        atomicAdd(&hist[copy * HSTRIDE + ((key >> shift) & 255u)], 1u);
      }
    }
    __syncthreads();

    if (threadIdx.x == 0) {
      unsigned int cum = 0;
      int d = 255;
      for (; d >= 0; --d) {
        unsigned int c = 0;
        for (int cp = 0; cp < NCOPY; ++cp) c += hist[cp * HSTRIDE + d];
        if (cum + c >= remaining) break;
        cum += c;
      }
      sel_digit = (unsigned int)d;
      sel_remaining = remaining - cum;
      tie_cnt = 0;
    }
    __syncthreads();
    prefix = (prefix << 8) | sel_digit;
    remaining = sel_remaining;
    __syncthreads();
  }

  // prefix == threshold key T; include all key>T, plus `remaining` of key==T
  const unsigned int T = prefix;
  float partial = 0.f;
  for (int i = threadIdx.x; i < HW; i += blockDim.x) {
    unsigned int key = mono_key(s[i]);
    if (key > T) {
      partial += ct[i];
    } else if (key == T) {
      unsigned int old = atomicAdd(&tie_cnt, 1u);
      if (old < remaining) partial += ct[i];
    }
  }

  red[threadIdx.x] = partial;
  __syncthreads();
  for (int off = 512; off > 0; off >>= 1) {
    if ((int)threadIdx.x < off) red[threadIdx.x] += red[threadIdx.x + off];
    __syncthreads();
  }
  if (threadIdx.x == 0) batch_sums[b] = red[0];
}

__global__ void finalize_kernel(const float* __restrict__ batch_sums,
                                const float* __restrict__ dx,
                                const float* __restrict__ dy,
                                const float* __restrict__ dth,
                                float* __restrict__ out) {
  if (threadIdx.x == 0 && blockIdx.x == 0) {
    float s = 0.f;
    for (int b = 0; b < BATCH; ++b) s += batch_sums[b];
    float align = s / (float)(BATCH * KSEL);
    float r1 = 0.f, r2 = 0.f;
    for (int b = 0; b < BATCH; ++b) {
      r1 += dx[b] * dx[b] + dy[b] * dy[b];
      r2 += dth[b] * dth[b];
    }
    r1 /= (float)BATCH;
    r2 /= (float)BATCH;
    out[0] = align + 0.1f * (r1 + r2);  // ALIGN_WEIGHT=1, REG_WEIGHT=0.1
  }
}

extern "C" void kernel_launch(void* const* d_in, const int* in_sizes, int n_in,
                              void* d_out, int out_size, void* d_ws, size_t ws_size,
                              hipStream_t stream) {
  const float* bev   = (const float*)d_in[0];
  const float* prior = (const float*)d_in[1];
  const float* dx    = (const float*)d_in[2];
  const float* dy    = (const float*)d_in[3];
  const float* dth   = (const float*)d_in[4];
  float* out = (float*)d_out;

  float* score   = (float*)d_ws;           // BATCH*HW floats
  float* contrib = score + BATCH * HW;     // BATCH*HW floats
  float* bsums   = contrib + BATCH * HW;   // BATCH floats

  const int total = BATCH * HW;
  pixel_stats_kernel<<<(total + 255) / 256, 256, 0, stream>>>(bev, prior, score, contrib);
  topk_sum_kernel<<<BATCH, 1024, 0, stream>>>(score, contrib, bsums);
  finalize_kernel<<<1, 64, 0, stream>>>(bsums, dx, dy, dth, out);
}

// Round 2
// 714.780 us; speedup vs baseline: 1.0603x; 1.0603x over previous
//
#include <hip/hip_runtime.h>
#include <math.h>

#define BATCH 8
#define CCH 256
#define HW 40000
#define HW4 (HW / 4)          // 10000 float4 pixels per row
#define KSEL 8000
#define EPS_LN 1e-6f
#define EPS_COS 1e-8f
#define SLICES 40             // blocks per batch for hist/sum passes
#define SLICE_LEN (HW / SLICES)

// ---- workspace layout (uint/float units) ----
// [0)        score    : BATCH*HW floats
// [320000)   contrib  : BATCH*HW floats
// [640000)   hist1    : BATCH*65536 uint
// [1164288)  hist2    : BATCH*65536 uint
// [1688576)  prefix   : 8 uint
// [1688584)  rem1     : 8 uint
// [1688592)  Tkey     : 8 uint
// [1688600)  rem2     : 8 uint
// [1688608)  tie      : 8 uint
// [1688616)  bsums    : 8 float
#define OFF_SCORE   0
#define OFF_CONTRIB 320000
#define OFF_HIST1   640000
#define OFF_HIST2   1164288
#define OFF_PREFIX  1688576
#define OFF_REM1    1688584
#define OFF_TKEY    1688592
#define OFF_REM2    1688600
#define OFF_TIE     1688608
#define OFF_BSUMS   1688616

__device__ __forceinline__ unsigned int mono_key(float x) {
  unsigned int u = __float_as_uint(x);
  return (u & 0x80000000u) ? ~u : (u | 0x80000000u);
}

// Zero hist1+hist2 (+ bsums). 1048576 uints starting at OFF_HIST1, plus 8 floats.
__global__ __launch_bounds__(256) void zero_kernel(unsigned int* __restrict__ ws) {
  const int n4 = (2 * BATCH * 65536) / 4;  // uint4 count over hist1+hist2
  uint4* p = (uint4*)(ws + OFF_HIST1);
  uint4 z = {0u, 0u, 0u, 0u};
  for (int i = blockIdx.x * blockDim.x + threadIdx.x; i < n4; i += gridDim.x * blockDim.x)
    p[i] = z;
  if (blockIdx.x == 0 && threadIdx.x < BATCH) ws[OFF_BSUMS + threadIdx.x] = 0u;
}

// One thread per 4 consecutive pixels: stream C=256 channels of both tensors,
// float4 loads (16 B/lane), emit score (raw sum a^2) and contrib (1 - cos sim).
__global__ __launch_bounds__(256) void pixel_stats_kernel(
    const float* __restrict__ A, const float* __restrict__ B,
    float* __restrict__ score, float* __restrict__ contrib) {
  int tid = blockIdx.x * blockDim.x + threadIdx.x;
  if (tid >= BATCH * HW4) return;
  int b = tid / HW4;
  int p4 = tid - b * HW4;
  const float4* a  = (const float4*)(A + (size_t)b * CCH * HW) + p4;
  const float4* bb = (const float4*)(B + (size_t)b * CCH * HW) + p4;

  float sa[4] = {0, 0, 0, 0}, ssa[4] = {0, 0, 0, 0};
  float sb[4] = {0, 0, 0, 0}, ssb[4] = {0, 0, 0, 0}, dab[4] = {0, 0, 0, 0};
#pragma unroll 4
  for (int c = 0; c < CCH; ++c) {
    float4 x = a[(size_t)c * HW4];
    float4 y = bb[(size_t)c * HW4];
    float xs[4] = {x.x, x.y, x.z, x.w};
    float ys[4] = {y.x, y.y, y.z, y.w};
#pragma unroll
    for (int j = 0; j < 4; ++j) {
      sa[j] += xs[j];
      ssa[j] = fmaf(xs[j], xs[j], ssa[j]);
      sb[j] += ys[j];
      ssb[j] = fmaf(ys[j], ys[j], ssb[j]);
      dab[j] = fmaf(xs[j], ys[j], dab[j]);
    }
  }

  float scv[4], cov[4];
  const float invC = 1.0f / (float)CCH;
#pragma unroll
  for (int j = 0; j < 4; ++j) {
    scv[j] = ssa[j];
    float mua = sa[j] * invC, mub = sb[j] * invC;
    float cssa = fmaxf(ssa[j] - (float)CCH * mua * mua, 0.f);
    float cssb = fmaxf(ssb[j] - (float)CCH * mub * mub, 0.f);
    float cdot = dab[j] - (float)CCH * mua * mub;
    float siga = sqrtf(cssa / (float)(CCH - 1)) + EPS_LN;
    float sigb = sqrtf(cssb / (float)(CCH - 1)) + EPS_LN;
    float num = cdot / (siga * sigb);
    float na = sqrtf(cssa) / siga;
    float nb = sqrtf(cssb) / sigb;
    cov[j] = 1.0f - num / (fmaxf(na, EPS_COS) * fmaxf(nb, EPS_COS));
  }
  int out = b * HW + p4 * 4;
  *(float4*)(score + out)   = make_float4(scv[0], scv[1], scv[2], scv[3]);
  *(float4*)(contrib + out) = make_float4(cov[0], cov[1], cov[2], cov[3]);
}

// Histogram of top 16 bits of mono keys. grid = BATCH*SLICES blocks.
__global__ __launch_bounds__(256) void hist1_kernel(
    const float* __restrict__ score, unsigned int* __restrict__ ws) {
  int b = blockIdx.x / SLICES;
  int sl = blockIdx.x - b * SLICES;
  const float* s = score + b * HW;
  unsigned int* h = ws + OFF_HIST1 + (b << 16);
  int base = sl * SLICE_LEN;
  for (int i = base + threadIdx.x; i < base + SLICE_LEN; i += 256) {
    unsigned int key = mono_key(s[i]);
    atomicAdd(&h[key >> 16], 1u);
  }
}

// Histogram of low 16 bits among keys whose top16 == prefix[b].
__global__ __launch_bounds__(256) void hist2_kernel(
    const float* __restrict__ score, unsigned int* __restrict__ ws) {
  int b = blockIdx.x / SLICES;
  int sl = blockIdx.x - b * SLICES;
  const float* s = score + b * HW;
  unsigned int pref = ws[OFF_PREFIX + b];
  unsigned int* h = ws + OFF_HIST2 + (b << 16);
  int base = sl * SLICE_LEN;
  for (int i = base + threadIdx.x; i < base + SLICE_LEN; i += 256) {
    unsigned int key = mono_key(s[i]);
    if ((key >> 16) == pref) atomicAdd(&h[key & 0xFFFFu], 1u);
  }
}

// Find, within a 65536-bin histogram, the highest bin index D such that
// count(bins > D) < K <= count(bins >= D). Parallel suffix scan over 1024
// chunk sums (64 bins/chunk), then a 64-iteration serial walk in the chunk.
// phase==0: hist1, K=KSEL -> writes prefix, rem1.
// phase==1: hist2, K=rem1 -> writes Tkey=(prefix<<16)|D, rem2, tie=0.
__global__ __launch_bounds__(1024) void select_kernel(unsigned int* __restrict__ ws,
                                                      int phase) {
  int b = blockIdx.x;
  const unsigned int* h = ws + (phase ? OFF_HIST2 : OFF_HIST1) + (b << 16);
  unsigned int K = phase ? ws[OFF_REM1 + b] : (unsigned int)KSEL;

  __shared__ unsigned int chunk[1024];
  __shared__ unsigned int suf[1024];
  __shared__ unsigned int s_chunk_idx, s_cum_above;
  __shared__ unsigned int bins[64];

  int t = threadIdx.x;
  unsigned int sum = 0;
#pragma unroll 8
  for (int i = 0; i < 64; ++i) sum += h[t * 64 + i];
  chunk[t] = sum;
  suf[t] = sum;
  __syncthreads();
  // Hillis-Steele inclusive suffix scan: suf[t] = sum of chunk[t..1023]
  for (int off = 1; off < 1024; off <<= 1) {
    unsigned int v = (t + off < 1024) ? suf[t + off] : 0u;
    __syncthreads();
    suf[t] += v;
    __syncthreads();
  }
  unsigned int above = (t == 1023) ? 0u : suf[t + 1];
  if (suf[t] >= K && above < K) { s_chunk_idx = (unsigned int)t; s_cum_above = above; }
  __syncthreads();
  if (t < 64) bins[t] = h[s_chunk_idx * 64 + t];
  __syncthreads();
  if (t == 0) {
    unsigned int cum = s_cum_above;
    int d = 63;
    for (; d >= 0; --d) {
      if (cum + bins[d] >= K) break;
      cum += bins[d];
    }
    unsigned int binidx = s_chunk_idx * 64 + (unsigned int)d;
    if (phase == 0) {
      ws[OFF_PREFIX + b] = binidx;
      ws[OFF_REM1 + b] = K - cum;
    } else {
      ws[OFF_TKEY + b] = (ws[OFF_PREFIX + b] << 16) | binidx;
      ws[OFF_REM2 + b] = K - cum;
      ws[OFF_TIE + b] = 0u;
    }
  }
}

// Sum contribs of top-k pixels: all key > T, plus rem2 counted ties at key == T.
__global__ __launch_bounds__(256) void sum_kernel(
    const float* __restrict__ score, const float* __restrict__ contrib,
    unsigned int* __restrict__ ws) {
  int b = blockIdx.x / SLICES;
  int sl = blockIdx.x - b * SLICES;
  const float* s = score + b * HW;
  const float* ct = contrib + b * HW;
  unsigned int T = ws[OFF_TKEY + b];
  unsigned int rem2 = ws[OFF_REM2 + b];

  float partial = 0.f;
  int base = sl * SLICE_LEN;
  for (int i = base + threadIdx.x; i < base + SLICE_LEN; i += 256) {
    unsigned int key = mono_key(s[i]);
    if (key > T) {
      partial += ct[i];
    } else if (key == T) {
      unsigned int old = atomicAdd(&ws[OFF_TIE + b], 1u);
      if (old < rem2) partial += ct[i];
    }
  }

  __shared__ float red[256];
  red[threadIdx.x] = partial;
  __syncthreads();
  for (int off = 128; off > 0; off >>= 1) {
    if (threadIdx.x < (unsigned)off) red[threadIdx.x] += red[threadIdx.x + off];
    __syncthreads();
  }
  if (threadIdx.x == 0) atomicAdd((float*)(ws + OFF_BSUMS) + b, red[0]);
}

__global__ void finalize_kernel(const unsigned int* __restrict__ ws,
                                const float* __restrict__ dx,
                                const float* __restrict__ dy,
                                const float* __restrict__ dth,
                                float* __restrict__ out) {
  if (threadIdx.x == 0 && blockIdx.x == 0) {
    const float* bsums = (const float*)(ws + OFF_BSUMS);
    float s = 0.f;
    for (int b = 0; b < BATCH; ++b) s += bsums[b];
    float align = s / (float)(BATCH * KSEL);
    float r1 = 0.f, r2 = 0.f;
    for (int b = 0; b < BATCH; ++b) {
      r1 += dx[b] * dx[b] + dy[b] * dy[b];
      r2 += dth[b] * dth[b];
    }
    out[0] = align + 0.1f * (r1 / (float)BATCH + r2 / (float)BATCH);
  }
}

extern "C" void kernel_launch(void* const* d_in, const int* in_sizes, int n_in,
                              void* d_out, int out_size, void* d_ws, size_t ws_size,
                              hipStream_t stream) {
  const float* bev   = (const float*)d_in[0];
  const float* prior = (const float*)d_in[1];
  const float* dx    = (const float*)d_in[2];
  const float* dy    = (const float*)d_in[3];
  const float* dth   = (const float*)d_in[4];
  float* out = (float*)d_out;

  unsigned int* ws = (unsigned int*)d_ws;
  float* score   = (float*)ws + OFF_SCORE;
  float* contrib = (float*)ws + OFF_CONTRIB;

  zero_kernel<<<256, 256, 0, stream>>>(ws);
  pixel_stats_kernel<<<(BATCH * HW4 + 255) / 256, 256, 0, stream>>>(bev, prior, score, contrib);
  hist1_kernel<<<BATCH * SLICES, 256, 0, stream>>>(score, ws);
  select_kernel<<<BATCH, 1024, 0, stream>>>(ws, 0);
  hist2_kernel<<<BATCH * SLICES, 256, 0, stream>>>(score, ws);
  select_kernel<<<BATCH, 1024, 0, stream>>>(ws, 1);
  sum_kernel<<<BATCH * SLICES, 256, 0, stream>>>(score, contrib, ws);
  finalize_kernel<<<1, 64, 0, stream>>>(ws, dx, dy, dth, out);
}